// Round 1
// baseline (1659.793 us; speedup 1.0000x reference)
//
#include <hip/hip_runtime.h>
#include <math.h>

// N = 100000 nodes, SEQ = 16, layers: 3 ->16 ->32 ->64 ->128 ->256 ->12(log_softmax)

__device__ __forceinline__ float elu_f(float v) { return v > 0.f ? v : expm1f(v); }

// ---------------------------------------------------------------- fc0: [N,3] -> [N,16]
__global__ __launch_bounds__(256) void fc0_kernel(const float* __restrict__ x,
                                                  const float* __restrict__ w,
                                                  const float* __restrict__ b,
                                                  float* __restrict__ h0, int N)
{
    int n = blockIdx.x * 256 + threadIdx.x;
    if (n >= N) return;
    float x0 = x[n * 3 + 0], x1 = x[n * 3 + 1], x2 = x[n * 3 + 2];
    float o[16];
#pragma unroll
    for (int j = 0; j < 16; ++j)
        o[j] = elu_f(w[j * 3 + 0] * x0 + w[j * 3 + 1] * x1 + w[j * 3 + 2] * x2 + b[j]);
    float4* dst = (float4*)&h0[(size_t)n * 16];
    dst[0] = make_float4(o[0], o[1], o[2], o[3]);
    dst[1] = make_float4(o[4], o[5], o[6], o[7]);
    dst[2] = make_float4(o[8], o[9], o[10], o[11]);
    dst[3] = make_float4(o[12], o[13], o[14], o[15]);
}

// ------------------------------------------- gather-GEMM: out[n,o] = elu(sum_k A[n,k] * W[o,k] + b[o])
// A[n, s*CIN + c] = hin[idx[n,s], c]   (GATHER) or hin[n, k] (dense, S==1)
template <int CIN, int S, int COUT, int TILE_M, int BK, bool GATHER>
__global__ __launch_bounds__(256) void spiral_kernel(const float* __restrict__ hin,
                                                     const int* __restrict__ idx,
                                                     const float* __restrict__ W,
                                                     const float* __restrict__ bias,
                                                     float* __restrict__ hout, int N)
{
    constexpr int K = CIN * S;
    constexpr int NSTEP = K / BK;
    constexpr int TN = 4;
    constexpr int TX = COUT / TN;   // threads along out-channel dim
    constexpr int TY = 256 / TX;    // thread groups along node dim
    constexpr int TM = TILE_M / TY; // nodes per thread
    static_assert(TX * TY == 256, "bad thread tiling");
    static_assert(TM * TY == TILE_M, "bad m tiling");
    constexpr int LPR = BK / 4;     // lanes per staged row (float4)
    constexpr int RPP = 256 / LPR;  // rows per staging pass
    static_assert((TILE_M % RPP == 0) || (RPP % TILE_M == 0), "stage A shape");
    static_assert(COUT % RPP == 0, "stage B shape");

    __shared__ __align__(16) float As[TILE_M][BK + 4];
    __shared__ __align__(16) float Bst[BK][COUT + 4];
    __shared__ int idx_s[GATHER ? TILE_M * S : 1];

    const int tid = threadIdx.x;
    const int m0 = blockIdx.x * TILE_M;

    if constexpr (GATHER) {
        for (int i = tid; i < TILE_M * S; i += 256) {
            int m = i / S;
            int gm = m0 + m;
            if (gm >= N) gm = N - 1;
            idx_s[i] = idx[(size_t)gm * S + (i % S)];
        }
    }

    float4 acc[TM];
#pragma unroll
    for (int i = 0; i < TM; ++i) acc[i] = make_float4(0.f, 0.f, 0.f, 0.f);

    const int tx = tid % TX;
    const int ty = tid / TX;

    for (int step = 0; step < NSTEP; ++step) {
        const int k0 = step * BK;
        __syncthreads();
        // ---- stage A (gathered) : TILE_M x BK
        {
            const int k4 = tid % LPR;
            const int colk = k0 + k4 * 4;
#pragma unroll
            for (int p = 0; p < (TILE_M + RPP - 1) / RPP; ++p) {
                int m = tid / LPR + p * RPP;
                if ((TILE_M % RPP != 0) && m >= TILE_M) break;
                int row;
                int col;
                if constexpr (GATHER) {
                    row = idx_s[m * S + colk / CIN];
                    col = colk % CIN;
                } else {
                    row = m0 + m;
                    if (row >= N) row = N - 1;
                    col = colk;
                }
                *(float4*)&As[m][k4 * 4] = *(const float4*)&hin[(size_t)row * CIN + col];
            }
        }
        // ---- stage B transposed: Bst[k][o] = W[o][k0+k]
        {
            const int k4 = tid % LPR;
            const int kk = k4 * 4;
#pragma unroll
            for (int p = 0; p < COUT / RPP; ++p) {
                int o = tid / LPR + p * RPP;
                float4 w4 = *(const float4*)&W[(size_t)o * K + k0 + kk];
                Bst[kk + 0][o] = w4.x;
                Bst[kk + 1][o] = w4.y;
                Bst[kk + 2][o] = w4.z;
                Bst[kk + 3][o] = w4.w;
            }
        }
        __syncthreads();
        // ---- compute
#pragma unroll
        for (int k = 0; k < BK; k += 4) {
            float4 b0 = *(float4*)&Bst[k + 0][tx * 4];
            float4 b1 = *(float4*)&Bst[k + 1][tx * 4];
            float4 b2 = *(float4*)&Bst[k + 2][tx * 4];
            float4 b3 = *(float4*)&Bst[k + 3][tx * 4];
#pragma unroll
            for (int i = 0; i < TM; ++i) {
                float4 a = *(float4*)&As[ty * TM + i][k];
                acc[i].x += a.x * b0.x + a.y * b1.x + a.z * b2.x + a.w * b3.x;
                acc[i].y += a.x * b0.y + a.y * b1.y + a.z * b2.y + a.w * b3.y;
                acc[i].z += a.x * b0.z + a.y * b1.z + a.z * b2.z + a.w * b3.z;
                acc[i].w += a.x * b0.w + a.y * b1.w + a.z * b2.w + a.w * b3.w;
            }
        }
    }

    // ---- epilogue: bias + ELU
    const int ob = tx * 4;
    const float bb0 = bias[ob + 0], bb1 = bias[ob + 1], bb2 = bias[ob + 2], bb3 = bias[ob + 3];
#pragma unroll
    for (int i = 0; i < TM; ++i) {
        int m = m0 + ty * TM + i;
        if (m < N) {
            float4 r;
            r.x = elu_f(acc[i].x + bb0);
            r.y = elu_f(acc[i].y + bb1);
            r.z = elu_f(acc[i].z + bb2);
            r.w = elu_f(acc[i].w + bb3);
            *(float4*)&hout[(size_t)m * COUT + ob] = r;
        }
    }
}

// ---------------------------------------------------------------- fc2 + log_softmax: [N,256] -> [N,12]
__global__ __launch_bounds__(256) void fc2_kernel(const float* __restrict__ h4,
                                                  const float* __restrict__ W,  // [12,256]
                                                  const float* __restrict__ b,
                                                  float* __restrict__ out, int N)
{
    __shared__ __align__(16) float ws[12 * 256];
    __shared__ float bs[12];
    for (int i = threadIdx.x; i < 12 * 256; i += 256) ws[i] = W[i];
    if (threadIdx.x < 12) bs[threadIdx.x] = b[threadIdx.x];
    __syncthreads();

    const int lane = threadIdx.x & 63;
    const int local = threadIdx.x >> 6;  // 4 nodes per block
    const int n = blockIdx.x * 4 + local;
    if (n >= N) return;

    float4 h = *(const float4*)&h4[(size_t)n * 256 + lane * 4];
    float p[12];
#pragma unroll
    for (int o = 0; o < 12; ++o) {
        float4 w4 = *(float4*)&ws[o * 256 + lane * 4];
        p[o] = h.x * w4.x + h.y * w4.y + h.z * w4.z + h.w * w4.w;
    }
#pragma unroll
    for (int off = 32; off > 0; off >>= 1) {
#pragma unroll
        for (int o = 0; o < 12; ++o) p[o] += __shfl_down(p[o], off);
    }
    if (lane == 0) {
        float logits[12], mx = -1e30f;
#pragma unroll
        for (int o = 0; o < 12; ++o) {
            logits[o] = p[o] + bs[o];
            mx = fmaxf(mx, logits[o]);
        }
        float s = 0.f;
#pragma unroll
        for (int o = 0; o < 12; ++o) s += expf(logits[o] - mx);
        float lse = mx + logf(s);
#pragma unroll
        for (int o = 0; o < 12; ++o) out[(size_t)n * 12 + o] = logits[o] - lse;
    }
}

extern "C" void kernel_launch(void* const* d_in, const int* in_sizes, int n_in,
                              void* d_out, int out_size, void* d_ws, size_t ws_size,
                              hipStream_t stream)
{
    const int N = 100000;
    const float* x     = (const float*)d_in[0];
    const int*   idx   = (const int*)  d_in[1];   // jnp.int64 downcast to int32 (x64 disabled)
    const float* fc0_w = (const float*)d_in[2];
    const float* fc0_b = (const float*)d_in[3];
    const float* w1    = (const float*)d_in[4];
    const float* b1    = (const float*)d_in[5];
    const float* w2    = (const float*)d_in[6];
    const float* b2    = (const float*)d_in[7];
    const float* w3    = (const float*)d_in[8];
    const float* b3    = (const float*)d_in[9];
    const float* fc1_w = (const float*)d_in[10];
    const float* fc1_b = (const float*)d_in[11];
    const float* fc2_w = (const float*)d_in[12];
    const float* fc2_b = (const float*)d_in[13];
    float* out = (float*)d_out;

    // scratch ping-pong: A holds h0/h2/h4 (max 256 ch), B holds h1/h3 (max 128 ch)
    char* ws = (char*)d_ws;
    const size_t sizeA = (size_t)N * 256 * sizeof(float);  // 102.4 MB
    float* bufA = (float*)ws;
    float* bufB = (float*)(ws + sizeA);
    float* h0 = bufA;  // [N,16]
    float* h1 = bufB;  // [N,32]
    float* h2 = bufA;  // [N,64]
    float* h3 = bufB;  // [N,128]
    float* h4 = bufA;  // [N,256]

    fc0_kernel<<<(N + 255) / 256, 256, 0, stream>>>(x, fc0_w, fc0_b, h0, N);
    spiral_kernel<16, 16, 32, 64, 64, true><<<(N + 63) / 64, 256, 0, stream>>>(h0, idx, w1, b1, h1, N);
    spiral_kernel<32, 16, 64, 64, 64, true><<<(N + 63) / 64, 256, 0, stream>>>(h1, idx, w2, b2, h2, N);
    spiral_kernel<64, 16, 128, 64, 64, true><<<(N + 63) / 64, 256, 0, stream>>>(h2, idx, w3, b3, h3, N);
    spiral_kernel<128, 1, 256, 32, 32, false><<<(N + 31) / 32, 256, 0, stream>>>(h3, nullptr, fc1_w, fc1_b, h4, N);
    fc2_kernel<<<(N + 3) / 4, 256, 0, stream>>>(h4, fc2_w, fc2_b, out, N);
}

// Round 2
// 360.161 us; speedup vs baseline: 4.6085x; 4.6085x over previous
//
#include <hip/hip_runtime.h>
#include <math.h>

// N = 100000 nodes, SEQ = 16, layers: 3 ->16 ->32 ->64 ->128 ->256 ->12(log_softmax)
// bf16 MFMA path: activations + weights in bf16, fp32 accumulate, fp32 log_softmax out.

typedef __bf16 bf16x8 __attribute__((ext_vector_type(8)));
typedef float f32x16 __attribute__((ext_vector_type(16)));

__device__ __forceinline__ float elu_f(float v) { return v > 0.f ? v : expm1f(v); }

// ------------------------------------------------ fused fp32 -> bf16 weight conversion
__global__ __launch_bounds__(256) void cvt5_kernel(const float* __restrict__ a, int na,
                                                   const float* __restrict__ b, int nb,
                                                   const float* __restrict__ c, int nc,
                                                   const float* __restrict__ d, int nd,
                                                   const float* __restrict__ e, int ne,
                                                   __bf16* __restrict__ dst)
{
    int i = blockIdx.x * 256 + threadIdx.x;
    int t01 = na + nb, t02 = t01 + nc, t03 = t02 + nd, t04 = t03 + ne;
    if (i >= t04) return;
    float v;
    if (i < na)       v = a[i];
    else if (i < t01) v = b[i - na];
    else if (i < t02) v = c[i - t01];
    else if (i < t03) v = d[i - t02];
    else              v = e[i - t03];
    dst[i] = (__bf16)v;
}

// ---------------------------------------------------------------- fc0: [N,3] -> [N,16] bf16
__global__ __launch_bounds__(256) void fc0_kernel(const float* __restrict__ x,
                                                  const float* __restrict__ w,
                                                  const float* __restrict__ b,
                                                  __bf16* __restrict__ h0, int N)
{
    int n = blockIdx.x * 256 + threadIdx.x;
    if (n >= N) return;
    float x0 = x[n * 3 + 0], x1 = x[n * 3 + 1], x2 = x[n * 3 + 2];
    __bf16 ob[16];
#pragma unroll
    for (int j = 0; j < 16; ++j)
        ob[j] = (__bf16)elu_f(w[j * 3 + 0] * x0 + w[j * 3 + 1] * x1 + w[j * 3 + 2] * x2 + b[j]);
    int4* dst = (int4*)&h0[(size_t)n * 16];
    dst[0] = *(int4*)&ob[0];
    dst[1] = *(int4*)&ob[8];
}

// ------------------------------------------- MFMA gather-GEMM
// out[n,o] = elu( sum_k A[n,k] * W[o,k] + bias[o] ),  A[n, s*CIN+c] = hin[idx[n,s], c]
// 32x32x16 bf16 MFMA; 4 waves as RW x CW grid; wave tile = (TILE_M/RW) x (COUT/CW).
template <int CIN, int S, int COUT, int TILE_M, int RW, int CW, bool GATHER>
__global__ __launch_bounds__(256) void mfma_layer(const __bf16* __restrict__ hin,
                                                  const int* __restrict__ idx,
                                                  const __bf16* __restrict__ Wb,
                                                  const float* __restrict__ bias,
                                                  __bf16* __restrict__ hout, int N)
{
    constexpr int K = CIN * S;
    constexpr int BK = 64;
    constexpr int NSTEP = K / BK;
    static_assert(K % BK == 0, "K%64");
    constexpr int WM = TILE_M / RW;   // rows per wave
    constexpr int WN = COUT / CW;     // cols per wave
    constexpr int MT = WM / 32;       // 32-row m-subtiles per wave
    constexpr int NT = WN / 32;       // 32-col n-subtiles per wave
    static_assert(RW * CW == 4, "4 waves");
    static_assert(WM % 32 == 0 && WN % 32 == 0, "tile mult of 32");

    constexpr int LDA = BK + 8;       // +8 bf16 pad -> 36-dword row stride
    __shared__ __align__(16) __bf16 As[TILE_M][LDA];
    __shared__ __align__(16) __bf16 Bs[COUT][LDA];
    __shared__ int idx_s[GATHER ? TILE_M * S : 1];

    const int tid = threadIdx.x;
    const int lane = tid & 63;
    const int w = tid >> 6;
    const int wr = w / CW;
    const int wc = w % CW;
    const int ml = lane & 31;
    const int kh = lane >> 5;
    const int m0 = blockIdx.x * TILE_M;

    if constexpr (GATHER) {
#pragma unroll
        for (int i = tid; i < TILE_M * S; i += 256) {
            int gm = m0 + i / S;
            if (gm >= N) gm = N - 1;
            idx_s[i] = idx[(size_t)gm * S + (i % S)];
        }
    }

    f32x16 acc[MT][NT];
#pragma unroll
    for (int mi = 0; mi < MT; ++mi)
#pragma unroll
        for (int ni = 0; ni < NT; ++ni) {
            f32x16 z = {};
            acc[mi][ni] = z;
        }

    for (int step = 0; step < NSTEP; ++step) {
        const int k0 = step * BK;
        __syncthreads();
        // ---- stage A: TILE_M x 64 bf16, 16B chunks (8 chunks/row)
#pragma unroll
        for (int i = tid; i < TILE_M * 8; i += 256) {
            int m = i >> 3;
            int c = i & 7;
            int kl = c * 8;
            const __bf16* src;
            if constexpr (GATHER) {
                int s_rel = kl / CIN;          // constexpr pow2 divide
                int cin_off = kl % CIN;
                int node = idx_s[m * S + k0 / CIN + s_rel];
                src = hin + (size_t)node * CIN + cin_off;
            } else {
                int gm = m0 + m;
                if (gm >= N) gm = N - 1;
                src = hin + (size_t)gm * K + k0 + kl;
            }
            *(int4*)&As[m][kl] = *(const int4*)src;
        }
        // ---- stage B: COUT x 64 bf16 from Wb[o][k0..k0+64)
#pragma unroll
        for (int i = tid; i < COUT * 8; i += 256) {
            int n = i >> 3;
            int c = i & 7;
            *(int4*)&Bs[n][c * 8] = *(const int4*)&Wb[(size_t)n * K + k0 + c * 8];
        }
        __syncthreads();
        // ---- compute: 4 k-subs of 16
#pragma unroll
        for (int ks = 0; ks < 4; ++ks) {
            const int kb = ks * 16 + kh * 8;
            bf16x8 a[MT], b[NT];
#pragma unroll
            for (int mi = 0; mi < MT; ++mi)
                a[mi] = *(const bf16x8*)&As[wr * WM + mi * 32 + ml][kb];
#pragma unroll
            for (int ni = 0; ni < NT; ++ni)
                b[ni] = *(const bf16x8*)&Bs[wc * WN + ni * 32 + ml][kb];
#pragma unroll
            for (int mi = 0; mi < MT; ++mi)
#pragma unroll
                for (int ni = 0; ni < NT; ++ni)
                    acc[mi][ni] = __builtin_amdgcn_mfma_f32_32x32x16_bf16(a[mi], b[ni], acc[mi][ni], 0, 0, 0);
        }
    }

    // ---- epilogue: bias + ELU + bf16 store
#pragma unroll
    for (int ni = 0; ni < NT; ++ni) {
        const int colg = wc * WN + ni * 32 + ml;
        const float bv = bias[colg];
#pragma unroll
        for (int mi = 0; mi < MT; ++mi) {
#pragma unroll
            for (int r = 0; r < 16; ++r) {
                int mrow = wr * WM + mi * 32 + ((r & 3) + 8 * (r >> 2) + 4 * kh);
                int gm = m0 + mrow;
                if (gm < N)
                    hout[(size_t)gm * COUT + colg] = (__bf16)elu_f(acc[mi][ni][r] + bv);
            }
        }
    }
}

// ---------------------------------------------------------------- fc2 + log_softmax: [N,256] bf16 -> [N,12] f32
// weights held in VGPRs (bf16), 2 nodes per wave-pass, width-32 shuffle reduce.
__global__ __launch_bounds__(256) void fc2_kernel(const __bf16* __restrict__ h4,
                                                  const __bf16* __restrict__ Wb,  // [12,256] bf16
                                                  const float* __restrict__ bias,
                                                  float* __restrict__ out, int N)
{
    const int lane = threadIdx.x & 63;
    const int w = threadIdx.x >> 6;
    const int c = lane & 31;   // k-chunk (8 bf16 each)
    const int half = lane >> 5;

    bf16x8 wreg[12];
#pragma unroll
    for (int o = 0; o < 12; ++o)
        wreg[o] = *(const bf16x8*)&Wb[o * 256 + c * 8];

    const int base = blockIdx.x * 32 + w * 8;
#pragma unroll
    for (int p = 0; p < 4; ++p) {
        int n = base + p * 2 + half;
        bool valid = n < N;
        int nn = valid ? n : N - 1;
        bf16x8 h = *(const bf16x8*)&h4[(size_t)nn * 256 + c * 8];
        float hf[8];
#pragma unroll
        for (int j = 0; j < 8; ++j) hf[j] = (float)h[j];
        float pr[12];
#pragma unroll
        for (int o = 0; o < 12; ++o) {
            float s = 0.f;
#pragma unroll
            for (int j = 0; j < 8; ++j) s += hf[j] * (float)wreg[o][j];
            pr[o] = s;
        }
#pragma unroll
        for (int off = 16; off > 0; off >>= 1) {
#pragma unroll
            for (int o = 0; o < 12; ++o) pr[o] += __shfl_down(pr[o], off, 32);
        }
        if (c == 0 && valid) {
            float logits[12], mx = -1e30f;
#pragma unroll
            for (int o = 0; o < 12; ++o) {
                logits[o] = pr[o] + bias[o];
                mx = fmaxf(mx, logits[o]);
            }
            float s = 0.f;
#pragma unroll
            for (int o = 0; o < 12; ++o) s += expf(logits[o] - mx);
            float lse = mx + logf(s);
#pragma unroll
            for (int o = 0; o < 12; ++o) out[(size_t)n * 12 + o] = logits[o] - lse;
        }
    }
}

extern "C" void kernel_launch(void* const* d_in, const int* in_sizes, int n_in,
                              void* d_out, int out_size, void* d_ws, size_t ws_size,
                              hipStream_t stream)
{
    const int N = 100000;
    const float* x     = (const float*)d_in[0];
    const int*   idx   = (const int*)  d_in[1];
    const float* fc0_w = (const float*)d_in[2];
    const float* fc0_b = (const float*)d_in[3];
    const float* w1    = (const float*)d_in[4];
    const float* b1    = (const float*)d_in[5];
    const float* w2    = (const float*)d_in[6];
    const float* b2    = (const float*)d_in[7];
    const float* w3    = (const float*)d_in[8];
    const float* b3    = (const float*)d_in[9];
    const float* fc1_w = (const float*)d_in[10];
    const float* fc1_b = (const float*)d_in[11];
    const float* fc2_w = (const float*)d_in[12];
    const float* fc2_b = (const float*)d_in[13];
    float* out = (float*)d_out;

    // ---- workspace layout (bf16 everywhere), ~100 MB total
    char* ws = (char*)d_ws;
    const int n_w1 = 32 * 256, n_w2 = 64 * 512, n_w3 = 128 * 1024, n_fc1 = 256 * 128, n_fc2 = 12 * 256;
    const int n_wb = n_w1 + n_w2 + n_w3 + n_fc1 + n_fc2;   // 207872
    __bf16* wb  = (__bf16*)ws;
    __bf16* w1b = wb;
    __bf16* w2b = w1b + n_w1;
    __bf16* w3b = w2b + n_w2;
    __bf16* f1b = w3b + n_w3;
    __bf16* f2b = f1b + n_fc1;
    size_t off = ((size_t)n_wb * 2 + 4095) & ~(size_t)4095;
    __bf16* h0 = (__bf16*)(ws + off);  off += (size_t)N * 16 * 2;
    __bf16* h1 = (__bf16*)(ws + off);  off += (size_t)N * 32 * 2;
    __bf16* h2 = (__bf16*)(ws + off);  off += (size_t)N * 64 * 2;
    __bf16* h3 = (__bf16*)(ws + off);  off += (size_t)N * 128 * 2;
    __bf16* h4 = (__bf16*)(ws + off);  off += (size_t)N * 256 * 2;

    cvt5_kernel<<<(n_wb + 255) / 256, 256, 0, stream>>>(w1, n_w1, w2, n_w2, w3, n_w3,
                                                        fc1_w, n_fc1, fc2_w, n_fc2, wb);
    fc0_kernel<<<(N + 255) / 256, 256, 0, stream>>>(x, fc0_w, fc0_b, h0, N);
    // spiral1: 16ch x16 -> 32
    mfma_layer<16, 16, 32, 128, 4, 1, true><<<(N + 127) / 128, 256, 0, stream>>>(h0, idx, w1b, b1, h1, N);
    // spiral2: 32ch x16 -> 64
    mfma_layer<32, 16, 64, 128, 2, 2, true><<<(N + 127) / 128, 256, 0, stream>>>(h1, idx, w2b, b2, h2, N);
    // spiral3: 64ch x16 -> 128
    mfma_layer<64, 16, 128, 128, 2, 2, true><<<(N + 127) / 128, 256, 0, stream>>>(h2, idx, w3b, b3, h3, N);
    // fc1: dense 128 -> 256
    mfma_layer<128, 1, 256, 64, 2, 2, false><<<(N + 63) / 64, 256, 0, stream>>>(h3, nullptr, f1b, fc1_b, h4, N);
    // fc2 + log_softmax
    fc2_kernel<<<(N + 31) / 32, 256, 0, stream>>>(h4, f2b, fc2_b, out, N);
}